// Round 10
// baseline (240.941 us; speedup 1.0000x reference)
//
#include <hip/hip_runtime.h>

#define V 255
#define L 16
#define E (V*L)      // 4080
#define P 8
#define CLIPV 10.0f

// tanh(0.5 * clip(s, -10, 10)) = 1 - 2/(exp(clip(s))+1)
__device__ __forceinline__ float tanh_half_clip(float s) {
    float t = fminf(fmaxf(s, -CLIPV), CLIPV);
    float e = __expf(t);
    return 1.0f - __fdividef(2.0f, e + 1.0f);
}

// zero-substitution (reference: e += (|e|==0))
__device__ __forceinline__ float zsub(float o) {
    return (o == 0.0f) ? 1.0f : o;
}

// Transposed layout: flat index i = row*16+col of [V][L] -> element col*V+row.
__device__ __forceinline__ int tr_elem(int i) {
    return (i & (L - 1)) * V + (i >> 4);
}

// One (b,p) unit per 256-thread block (17.3 KB LDS -> 8 blocks/CU = 32
// waves/CU). Fused even+odd via cr(rc(i)) == i: the even value consumed on
// edge l is logratio(total[row(rc(v,l))] / e_own[v,l]); e_own is this
// thread's own zsub'd odd output, so ev never round-trips LDS -- only the
// published e's and the 255-entry row-totals table do.
template <int MODE>
__global__ __launch_bounds__(256, 8) void bps_kernel(
    const float* __restrict__ x,
    const float* __restrict__ oddw_v,
    const float* __restrict__ oddw_e,
    const float* __restrict__ w_e_out,
    const int*   __restrict__ perma,
    const int*   __restrict__ rc_idx,
    const int*   __restrict__ cr_idx,
    float* __restrict__ eo_ws,     // MODE 0
    const int* __restrict__ invp,  // MODE 1
    float* __restrict__ out)       // MODE 1
{
    __shared__ float OO[E];        // zsub'd odd outputs, col-major [l][v]
    __shared__ float TOT[V + 1];   // per-row products

    const int tid  = threadIdx.x;
    const int unit = blockIdx.x;       // (b,p)
    const int b = unit >> 3;
    const int p = unit & 7;
    const int v = tid;
    const bool act = (v < V);

    float xv = 0.0f;
    unsigned pk[L];   // lo16: LDS elem idx for cr-gather; hi16: row(rc) for TOT
    if (act) {
        xv = x[b * (V + 1) + perma[p * (V + 1) + v + 1]];
        const int4* rc4 = (const int4*)(rc_idx + v * L);
        const int4* cr4 = (const int4*)(cr_idx + v * L);
#pragma unroll
        for (int i = 0; i < 4; ++i) {
            int4 a = rc4[i];
            int4 c = cr4[i];
            pk[4*i+0] = (unsigned)tr_elem(c.x) | ((unsigned)(a.x >> 4) << 16);
            pk[4*i+1] = (unsigned)tr_elem(c.y) | ((unsigned)(a.y >> 4) << 16);
            pk[4*i+2] = (unsigned)tr_elem(c.z) | ((unsigned)(a.z >> 4) << 16);
            pk[4*i+3] = (unsigned)tr_elem(c.w) | ((unsigned)(a.w >> 4) << 16);
        }
    }

    // ---- t=0 odd layer (message==0 -> rank-1), zsub'd ----
    float ev[L];   // e entering the even phase; then logratio outputs
    if (act) {
#pragma unroll
        for (int m = 0; m < L; ++m)
            ev[m] = zsub(tanh_half_clip(xv * oddw_v[m]));   // uniform s_load
    }

#pragma unroll 1
    for (int t = 0; t < 5; ++t) {
        // ---- A: publish e (conflict-free column writes) ----
        if (act) {
#pragma unroll
            for (int m = 0; m < L; ++m) OO[m * V + v] = ev[m];
        }
        __syncthreads();

        // ---- C: cr-gather + tree product -> row total ----
        if (act) {
            float t0 = 1.0f, t1 = 1.0f, t2 = 1.0f, t3 = 1.0f;
#pragma unroll
            for (int l = 0; l < L; l += 4) {
                t0 *= OO[pk[l + 0] & 0xffffu];
                t1 *= OO[pk[l + 1] & 0xffffu];
                t2 *= OO[pk[l + 2] & 0xffffu];
                t3 *= OO[pk[l + 3] & 0xffffu];
            }
            TOT[v] = (t0 * t1) * (t2 * t3);
        }
        __syncthreads();

        // ---- F: fused logratio; then odd matvec fully in registers ----
        // r = T/e; log((1+r)/(1-r+1e-9)+1e-9) == log((e+T)/(e-T+1e-9*e))
        // to ~1e-6 (|r| <= tanh(5)^15 ~ 0.9986, args stay well-positive;
        // t=0 clip(r,+-10) is an identity since |r|<1).
        if (act) {
#pragma unroll
            for (int l = 0; l < L; ++l) {
                float Tl = TOT[pk[l] >> 16];
                float e  = ev[l];
                float num = e + Tl;
                float den = fmaf(e, 1e-9f, e - Tl);
                ev[l] = __logf(__fdividef(num, den));
            }
            if (t < 4) {
                const float* __restrict__ wv = oddw_v + (t + 1) * L;
                const float* __restrict__ wm = oddw_e + (t + 1) * (L * L);
                float s[L];
#pragma unroll
                for (int m = 0; m < L; ++m) s[m] = xv * wv[m];  // uniform s_load
#pragma unroll
                for (int l = 0; l < L; ++l) {
                    const float el = ev[l];
#pragma unroll
                    for (int m = 0; m < L; ++m) {
                        if (m != l)                    // diag mask, compile-time
                            s[m] = fmaf(el, wm[l * L + m], s[m]);
                    }
                }
#pragma unroll
                for (int m = 0; m < L; ++m)
                    ev[m] = zsub(tanh_half_clip(s[m]));
            }
        }
    }

    // ---- final: dot with w_e_out straight from registers ----
    if (act) {
        float d = 0.0f;
#pragma unroll
        for (int l = 0; l < L; ++l)
            d = fmaf(ev[l], w_e_out[l], d);
        if (MODE == 0) {
            eo_ws[(size_t)unit * V + v] = d;
        } else {
            int j = invp[p * (V + 1) + (v + 1)];
            atomicAdd(&out[b * (V + 1) + j], d);
        }
    }
}

// gather-sum epilogue (MODE 0 path)
__global__ __launch_bounds__(256) void out_kernel(
    const float* __restrict__ x,
    const float* __restrict__ eo_ws,
    const int* __restrict__ perma,
    float* __restrict__ out)
{
    const int b = blockIdx.x;
    const int j = threadIdx.x;   // 0..255
    float acc = x[b * (V + 1) + j];
#pragma unroll
    for (int p = 0; p < P; ++p) {
        int idx = perma[p * (V + 1) + j];
        if (idx > 0) acc += eo_ws[((size_t)(b * P + p)) * V + (idx - 1)];
    }
    out[b * (V + 1) + j] = acc;
}

// fallback helpers (MODE 1 path)
__global__ __launch_bounds__(256) void inv_kernel(const int* __restrict__ perma,
                                                  int* __restrict__ invp)
{
    int p = blockIdx.x, j = threadIdx.x;
    invp[p * (V + 1) + perma[p * (V + 1) + j]] = j;
}

__global__ __launch_bounds__(256) void copy_kernel(const float* __restrict__ x,
                                                   float* __restrict__ out, int n)
{
    int i = blockIdx.x * 256 + threadIdx.x;
    if (i < n) out[i] = x[i];
}

extern "C" void kernel_launch(void* const* d_in, const int* in_sizes, int n_in,
                              void* d_out, int out_size, void* d_ws, size_t ws_size,
                              hipStream_t stream)
{
    const float* x       = (const float*)d_in[0];
    const float* oddw_v  = (const float*)d_in[2];
    const float* oddw_e  = (const float*)d_in[3];
    const float* w_e_out = (const float*)d_in[4];
    const int*   perma   = (const int*)d_in[5];
    const int*   rc      = (const int*)d_in[6];
    const int*   cr      = (const int*)d_in[7];
    float* out = (float*)d_out;

    const int Bx = in_sizes[0] / (V + 1);
    const int nunits = Bx * P;
    const size_t need = (size_t)nunits * V * sizeof(float);

    if (ws_size >= need) {
        float* eo = (float*)d_ws;
        hipLaunchKernelGGL((bps_kernel<0>), dim3(nunits), dim3(256), 0, stream,
                           x, oddw_v, oddw_e, w_e_out, perma, rc, cr,
                           eo, (const int*)nullptr, (float*)nullptr);
        hipLaunchKernelGGL(out_kernel, dim3(Bx), dim3(256), 0, stream,
                           x, eo, perma, out);
    } else {
        // atomic fallback: needs P*(V+1)*4 = 8KB workspace for inverse perm
        int* invp = (int*)d_ws;
        hipLaunchKernelGGL(inv_kernel, dim3(P), dim3(V + 1), 0, stream, perma, invp);
        hipLaunchKernelGGL(copy_kernel, dim3((out_size + 255) / 256), dim3(256), 0, stream,
                           x, out, out_size);
        hipLaunchKernelGGL((bps_kernel<1>), dim3(nunits), dim3(256), 0, stream,
                           x, oddw_v, oddw_e, w_e_out, perma, rc, cr,
                           (float*)nullptr, invp, out);
    }
}